// Round 4
// baseline (932.360 us; speedup 1.0000x reference)
//
#include <hip/hip_runtime.h>
#include <hip/hip_fp16.h>

#define TT 512
#define BB 128
#define HH 128

typedef _Float16 half8_t __attribute__((ext_vector_type(8)));
typedef float    float4_t __attribute__((ext_vector_type(4)));

__device__ __forceinline__ float sigmoidf_fast(float x) {
    return 1.0f / (1.0f + __expf(-x));
}
__device__ __forceinline__ float tanhf_fast(float x) {
    return 2.0f / (1.0f + __expf(-2.0f * x)) - 1.0f;
}

// xp layout (f16): half index = ((((dir*8+bg)*512 + t)*8 + w)*64 + lane)*16 + (T*4+r)
// i.e. for each (chain-group, t, wave, lane): 16 contiguous halfs in D-fragment
// order [T*4+r], so the recurrence acc-init is two coalesced 16B loads per lane.
__device__ __forceinline__ size_t xp_off(int dirbg, int t, int w, int lane) {
    return ((((size_t)dirbg * 512 + t) * 8 + w) * 64 + lane) * 16;
}

// ---- kernel 1: xp GEMM. WG=(dir*8+bg, tchunk): M=16 chains, N=512 gates, K=128.
// 8 waves; wave w owns N-tiles {T*128+16w .. +16} for T=0..3 (matches recurrence).
// B-frags (Wih) register-resident across the 32-t chunk; bias pre-folded into acc.
__global__ __launch_bounds__(512) void xp_gemm_kernel(
    const int* __restrict__ x, const float* __restrict__ emb,
    const float* __restrict__ Wih_f, const float* __restrict__ bih_f, const float* __restrict__ bhh_f,
    const float* __restrict__ Wih_b, const float* __restrict__ bih_b, const float* __restrict__ bhh_b,
    _Float16* __restrict__ xp)
{
    const int wg  = blockIdx.x;        // dir*8+bg
    const int dir = wg >> 3, bg = wg & 7;
    const int tc  = blockIdx.y;        // t-base = tc*32

    const float* Wih = dir ? Wih_b : Wih_f;
    const float* bih = dir ? bih_b : bih_f;
    const float* bhh = dir ? bhh_b : bhh_f;

    const int tid = threadIdx.x;
    const int w = tid >> 6, lane = tid & 63, lq = lane >> 4, lm = lane & 15;

    __shared__ int id_sm[16 * 32];
    __shared__ _Float16 A[2][16 * 136];   // +8 halfs row pad: conflict-free b128 reads

    {   // token ids for this (chain-group, t-chunk)
        int i = tid >> 5, j = tid & 31;
        id_sm[i * 32 + j] = x[(size_t)(bg * 16 + i) * TT + tc * 32 + j];
    }

    // B-frags + bias (loop-invariant)
    half8_t bf[4][4];
    float bias[4];
    #pragma unroll
    for (int T = 0; T < 4; ++T) {
        int gate = T * 128 + w * 16 + lm;
        bias[T] = bih[gate] + bhh[gate];
        #pragma unroll
        for (int kk = 0; kk < 4; ++kk) {
            const float* src = Wih + (size_t)gate * 128 + kk * 32 + lq * 8;
            half8_t h;
            #pragma unroll
            for (int j = 0; j < 8; ++j) h[j] = (_Float16)src[j];
            bf[T][kk] = h;
        }
    }
    __syncthreads();

    const int i = tid >> 5, seg = tid & 31;   // A-staging role: row i, 4-float seg
    {   // stage t'=0
        int id = id_sm[i * 32];
        float4 v = *(const float4*)(emb + (size_t)id * 128 + seg * 4);
        _Float16* d = &A[0][i * 136 + seg * 4];
        d[0] = (_Float16)v.x; d[1] = (_Float16)v.y;
        d[2] = (_Float16)v.z; d[3] = (_Float16)v.w;
    }
    __syncthreads();

    for (int tp = 0; tp < 32; ++tp) {
        const int buf = tp & 1;
        // prefetch next t's embedding rows (global gather, hidden under MFMA)
        float4 v;
        const bool havepre = (tp + 1 < 32);
        if (havepre) {
            int id = id_sm[i * 32 + tp + 1];
            v = *(const float4*)(emb + (size_t)id * 128 + seg * 4);
        }

        half8_t af[4];
        #pragma unroll
        for (int kk = 0; kk < 4; ++kk)
            af[kk] = *(const half8_t*)&A[buf][lm * 136 + kk * 32 + lq * 8];

        float4_t acc[4];
        #pragma unroll
        for (int T = 0; T < 4; ++T)
            acc[T] = (float4_t){bias[T], bias[T], bias[T], bias[T]};
        #pragma unroll
        for (int kk = 0; kk < 4; ++kk) {
            #pragma unroll
            for (int T = 0; T < 4; ++T)
                acc[T] = __builtin_amdgcn_mfma_f32_16x16x32_f16(af[kk], bf[T][kk], acc[T], 0, 0, 0);
        }

        // pack D-order halfs [T*4+r] and store 32B contiguous per lane
        half8_t p0, p1;
        #pragma unroll
        for (int T = 0; T < 2; ++T)
            #pragma unroll
            for (int r = 0; r < 4; ++r) p0[T * 4 + r] = (_Float16)acc[T][r];
        #pragma unroll
        for (int T = 2; T < 4; ++T)
            #pragma unroll
            for (int r = 0; r < 4; ++r) p1[(T - 2) * 4 + r] = (_Float16)acc[T][r];
        half8_t* dst = (half8_t*)(xp + xp_off(wg, tc * 32 + tp, w, lane));
        dst[0] = p0; dst[1] = p1;

        if (havepre) {
            _Float16* d = &A[1 - buf][i * 136 + seg * 4];
            d[0] = (_Float16)v.x; d[1] = (_Float16)v.y;
            d[2] = (_Float16)v.z; d[3] = (_Float16)v.w;
        }
        __syncthreads();
    }
}

// ---- kernel 2: MFMA-batched recurrence. WG=(dir*8+bg): 16 chains/WG, 16 WGs.
// Wave w owns h-range [16w,16w+16) for ALL 4 gate types -> i,f,g,o for a given
// (chain,h) sit in the same lane (regs acc[0..3][r]) -> in-register c/h update,
// ONE barrier per step. h exchanged via double-buffered LDS tile (A-frag layout).
__global__ __launch_bounds__(512) void bilstm_rec_kernel(
    const _Float16* __restrict__ xp,
    const float* __restrict__ Whh_f, const float* __restrict__ Whh_b,
    float* __restrict__ pooled)
{
    const int wg  = blockIdx.x;
    const int dir = wg >> 3, bg = wg & 7;
    const float* Whh = dir ? Whh_b : Whh_f;

    const int tid = threadIdx.x;
    const int w = tid >> 6, lane = tid & 63, lq = lane >> 4, lm = lane & 15;

    __shared__ _Float16 hsm[2][16 * 136];   // [buf][chain][h], +8 pad

    // Whh B-frags, register-resident for all 512 steps (64 VGPRs)
    half8_t bf[4][4];
    #pragma unroll
    for (int T = 0; T < 4; ++T) {
        #pragma unroll
        for (int kk = 0; kk < 4; ++kk) {
            const float* src = Whh + (size_t)(T * 128 + w * 16 + lm) * 128 + kk * 32 + lq * 8;
            half8_t h;
            #pragma unroll
            for (int j = 0; j < 8; ++j) h[j] = (_Float16)src[j];
            bf[T][kk] = h;
        }
    }

    for (int k = tid; k < 2 * 16 * 136; k += 512)
        ((_Float16*)hsm)[k] = (_Float16)0.0f;

    // per-(wave,lane) xp base; time stride = 8*64*16 halfs
    const _Float16* xp_wl = xp + ((size_t)wg * 512 * 8 + w) * 64 * 16 + (size_t)lane * 16;

    // preload xp for t=0
    int ta0 = dir ? (TT - 1) : 0;
    half8_t xca = *(const half8_t*)(xp_wl + (size_t)ta0 * 8192);
    half8_t xcb = *((const half8_t*)(xp_wl + (size_t)ta0 * 8192) + 1);
    __syncthreads();

    float c[4] = {0.f, 0.f, 0.f, 0.f};
    float hmax[4] = {-1e30f, -1e30f, -1e30f, -1e30f};

    for (int t = 0; t < TT; ++t) {
        const int buf = t & 1;

        // prefetch next step's xp (coalesced 32B/lane; hidden under MFMA+VALU)
        int tn = (t + 1 < TT) ? (t + 1) : t;
        int ta = dir ? (TT - 1 - tn) : tn;
        const half8_t* xsrc = (const half8_t*)(xp_wl + (size_t)ta * 8192);
        half8_t xna = xsrc[0], xnb = xsrc[1];

        // h A-frags (chain = lm): 4x ds_read_b128, conflict-free (136-half rows)
        half8_t af[4];
        #pragma unroll
        for (int kk = 0; kk < 4; ++kk)
            af[kk] = *(const half8_t*)&hsm[buf][lm * 136 + kk * 32 + lq * 8];

        // acc init from current xp (bias already folded in)
        float4_t acc[4];
        acc[0] = (float4_t){(float)xca[0], (float)xca[1], (float)xca[2], (float)xca[3]};
        acc[1] = (float4_t){(float)xca[4], (float)xca[5], (float)xca[6], (float)xca[7]};
        acc[2] = (float4_t){(float)xcb[0], (float)xcb[1], (float)xcb[2], (float)xcb[3]};
        acc[3] = (float4_t){(float)xcb[4], (float)xcb[5], (float)xcb[6], (float)xcb[7]};
        #pragma unroll
        for (int kk = 0; kk < 4; ++kk) {
            #pragma unroll
            for (int T = 0; T < 4; ++T)
                acc[T] = __builtin_amdgcn_mfma_f32_16x16x32_f16(af[kk], bf[T][kk], acc[T], 0, 0, 0);
        }

        // in-register gate math: lane's (chain = lq*4+r, h = w*16+lm)
        #pragma unroll
        for (int r = 0; r < 4; ++r) {
            float ig = sigmoidf_fast(acc[0][r]);
            float fg = sigmoidf_fast(acc[1][r]);
            float gg = tanhf_fast(acc[2][r]);
            float og = sigmoidf_fast(acc[3][r]);
            c[r] = fg * c[r] + ig * gg;
            float hv = og * tanhf_fast(c[r]);
            hmax[r] = fmaxf(hmax[r], hv);
            hsm[1 - buf][(lq * 4 + r) * 136 + w * 16 + lm] = (_Float16)hv;
        }

        xca = xna; xcb = xnb;
        __syncthreads();
    }

    #pragma unroll
    for (int r = 0; r < 4; ++r)
        pooled[(size_t)(bg * 16 + lq * 4 + r) * 256 + dir * HH + w * 16 + lm] = hmax[r];
}

// ---- kernel 3: pooled (128,256) -> relu(W1·+b1) -> sigmoid(W2·+b2) -> (128,1)
__global__ __launch_bounds__(64) void mlp_kernel(
    const float* __restrict__ pooled, const float* __restrict__ W1,
    const float* __restrict__ b1, const float* __restrict__ W2,
    const float* __restrict__ b2, float* __restrict__ out)
{
    const int b = blockIdx.x;
    const int j = threadIdx.x;
    const float4* p = (const float4*)(pooled + (size_t)b * 256);
    const float4* wv = (const float4*)(W1 + (size_t)j * 256);
    float s = 0.0f;
    #pragma unroll
    for (int q = 0; q < 64; ++q) {
        float4 pv = p[q];
        float4 ww = wv[q];
        s += pv.x * ww.x + pv.y * ww.y + pv.z * ww.z + pv.w * ww.w;
    }
    s += b1[j];
    s = fmaxf(s, 0.0f);
    float v = W2[j] * s;
    #pragma unroll
    for (int off = 32; off; off >>= 1) v += __shfl_down(v, off);
    if (j == 0) out[b] = 1.0f / (1.0f + __expf(-(v + b2[0])));
}

extern "C" void kernel_launch(void* const* d_in, const int* in_sizes, int n_in,
                              void* d_out, int out_size, void* d_ws, size_t ws_size,
                              hipStream_t stream) {
    const int*   x     = (const int*)d_in[0];
    const float* emb   = (const float*)d_in[1];
    const float* Wih_f = (const float*)d_in[2];
    const float* Whh_f = (const float*)d_in[3];
    const float* bih_f = (const float*)d_in[4];
    const float* bhh_f = (const float*)d_in[5];
    const float* Wih_b = (const float*)d_in[6];
    const float* Whh_b = (const float*)d_in[7];
    const float* bih_b = (const float*)d_in[8];
    const float* bhh_b = (const float*)d_in[9];
    const float* W1    = (const float*)d_in[10];
    const float* b1    = (const float*)d_in[11];
    const float* W2    = (const float*)d_in[12];
    const float* b2    = (const float*)d_in[13];
    float* out = (float*)d_out;

    char* ws = (char*)d_ws;
    float*    pooled = (float*)ws;                 // 128 KB
    _Float16* xp     = (_Float16*)(ws + 131072);   // 134.2 MB: 67,108,864 halfs

    hipLaunchKernelGGL(xp_gemm_kernel, dim3(16, 16), dim3(512), 0, stream,
                       x, emb, Wih_f, bih_f, bhh_f, Wih_b, bih_b, bhh_b, xp);
    hipLaunchKernelGGL(bilstm_rec_kernel, dim3(16), dim3(512), 0, stream,
                       xp, Whh_f, Whh_b, pooled);
    hipLaunchKernelGGL(mlp_kernel, dim3(128), dim3(64), 0, stream,
                       pooled, W1, b1, W2, b2, out);
}

// Round 5
// 928.133 us; speedup vs baseline: 1.0046x; 1.0046x over previous
//
#include <hip/hip_runtime.h>
#include <hip/hip_fp16.h>

#define TT 512
#define BB 128
#define HH 128

typedef _Float16 half8_t __attribute__((ext_vector_type(8)));
typedef float    float4_t __attribute__((ext_vector_type(4)));

__device__ __forceinline__ float sigmoidf_fast(float x) {
    return 1.0f / (1.0f + __expf(-x));
}
__device__ __forceinline__ float tanhf_fast(float x) {
    return 2.0f / (1.0f + __expf(-2.0f * x)) - 1.0f;
}

// xp layout (f16): half index = ((((dir*8+bg)*512 + t)*8 + w)*64 + lane)*16 + (T*4+r)
// i.e. for each (chain-group, t, wave, lane): 16 contiguous halfs in D-fragment
// order [T*4+r], so the recurrence acc-init is two coalesced 16B loads per lane.
__device__ __forceinline__ size_t xp_off(int dirbg, int t, int w, int lane) {
    return ((((size_t)dirbg * 512 + t) * 8 + w) * 64 + lane) * 16;
}

// ---- kernel 1: xp GEMM. WG=(dir*8+bg, tchunk): M=16 chains, N=512 gates, K=128.
// 8 waves; wave w owns N-tiles {T*128+16w .. +16} for T=0..3 (matches recurrence).
// B-frags (Wih) register-resident across the 32-t chunk; bias pre-folded into acc.
// waves_per_eu(2,2): exactly 2 waves/EU -> 256-VGPR budget; demand ~130 regs
// (64 bf + 16 af + 16 acc + temps) fits without AGPR churn (r4: default cap
// 128 forced accvgpr shuffle, 4x VALU bloat).
__global__ __attribute__((amdgpu_flat_work_group_size(512, 512), amdgpu_waves_per_eu(2, 2)))
void xp_gemm_kernel(
    const int* __restrict__ x, const float* __restrict__ emb,
    const float* __restrict__ Wih_f, const float* __restrict__ bih_f, const float* __restrict__ bhh_f,
    const float* __restrict__ Wih_b, const float* __restrict__ bih_b, const float* __restrict__ bhh_b,
    _Float16* __restrict__ xp)
{
    const int wg  = blockIdx.x;        // dir*8+bg
    const int dir = wg >> 3, bg = wg & 7;
    const int tc  = blockIdx.y;        // t-base = tc*32

    const float* Wih = dir ? Wih_b : Wih_f;
    const float* bih = dir ? bih_b : bih_f;
    const float* bhh = dir ? bhh_b : bhh_f;

    const int tid = threadIdx.x;
    const int w = tid >> 6, lane = tid & 63, lq = lane >> 4, lm = lane & 15;

    __shared__ int id_sm[16 * 32];
    __shared__ _Float16 A[2][16 * 136];   // +8 halfs row pad: conflict-free b128 reads

    {   // token ids for this (chain-group, t-chunk)
        int i = tid >> 5, j = tid & 31;
        id_sm[i * 32 + j] = x[(size_t)(bg * 16 + i) * TT + tc * 32 + j];
    }

    // B-frags + bias (loop-invariant)
    half8_t bf[4][4];
    float bias[4];
    #pragma unroll
    for (int T = 0; T < 4; ++T) {
        int gate = T * 128 + w * 16 + lm;
        bias[T] = bih[gate] + bhh[gate];
        #pragma unroll
        for (int kk = 0; kk < 4; ++kk) {
            const float* src = Wih + (size_t)gate * 128 + kk * 32 + lq * 8;
            half8_t h;
            #pragma unroll
            for (int j = 0; j < 8; ++j) h[j] = (_Float16)src[j];
            bf[T][kk] = h;
        }
    }
    __syncthreads();

    const int i = tid >> 5, seg = tid & 31;   // A-staging role: row i, 4-float seg
    {   // stage t'=0
        int id = id_sm[i * 32];
        float4 v = *(const float4*)(emb + (size_t)id * 128 + seg * 4);
        _Float16* d = &A[0][i * 136 + seg * 4];
        d[0] = (_Float16)v.x; d[1] = (_Float16)v.y;
        d[2] = (_Float16)v.z; d[3] = (_Float16)v.w;
    }
    __syncthreads();

    for (int tp = 0; tp < 32; ++tp) {
        const int buf = tp & 1;
        // prefetch next t's embedding rows (global gather, hidden under MFMA)
        float4 v;
        const bool havepre = (tp + 1 < 32);
        if (havepre) {
            int id = id_sm[i * 32 + tp + 1];
            v = *(const float4*)(emb + (size_t)id * 128 + seg * 4);
        }

        half8_t af[4];
        #pragma unroll
        for (int kk = 0; kk < 4; ++kk)
            af[kk] = *(const half8_t*)&A[buf][lm * 136 + kk * 32 + lq * 8];

        float4_t acc[4];
        #pragma unroll
        for (int T = 0; T < 4; ++T)
            acc[T] = (float4_t){bias[T], bias[T], bias[T], bias[T]};
        #pragma unroll
        for (int kk = 0; kk < 4; ++kk) {
            #pragma unroll
            for (int T = 0; T < 4; ++T)
                acc[T] = __builtin_amdgcn_mfma_f32_16x16x32_f16(af[kk], bf[T][kk], acc[T], 0, 0, 0);
        }

        // pack D-order halfs [T*4+r] and store 32B contiguous per lane
        half8_t p0, p1;
        #pragma unroll
        for (int T = 0; T < 2; ++T)
            #pragma unroll
            for (int r = 0; r < 4; ++r) p0[T * 4 + r] = (_Float16)acc[T][r];
        #pragma unroll
        for (int T = 2; T < 4; ++T)
            #pragma unroll
            for (int r = 0; r < 4; ++r) p1[(T - 2) * 4 + r] = (_Float16)acc[T][r];
        half8_t* dst = (half8_t*)(xp + xp_off(wg, tc * 32 + tp, w, lane));
        dst[0] = p0; dst[1] = p1;

        if (havepre) {
            _Float16* d = &A[1 - buf][i * 136 + seg * 4];
            d[0] = (_Float16)v.x; d[1] = (_Float16)v.y;
            d[2] = (_Float16)v.z; d[3] = (_Float16)v.w;
        }
        __syncthreads();
    }
}

// ---- kernel 2: MFMA-batched recurrence. WG=(dir*8+bg): 16 chains/WG, 16 WGs.
// Wave w owns h-range [16w,16w+16) for ALL 4 gate types -> i,f,g,o for a given
// (chain,h) sit in the same lane (regs acc[0..3][r]) -> in-register c/h update,
// ONE barrier per step. h exchanged via double-buffered LDS tile (A-frag layout).
// waves_per_eu(2,2): 256-VGPR budget so the 64-reg Whh fragment set + acc +
// xp double-buffer (~148 regs) stays in VGPRs (r4 default capped at 128 ->
// AGPR churn -> per-active-CU VALUBusy ~83% on shuffle ops, 3630 cyc/step).
__global__ __attribute__((amdgpu_flat_work_group_size(512, 512), amdgpu_waves_per_eu(2, 2)))
void bilstm_rec_kernel(
    const _Float16* __restrict__ xp,
    const float* __restrict__ Whh_f, const float* __restrict__ Whh_b,
    float* __restrict__ pooled)
{
    const int wg  = blockIdx.x;
    const int dir = wg >> 3, bg = wg & 7;
    const float* Whh = dir ? Whh_b : Whh_f;

    const int tid = threadIdx.x;
    const int w = tid >> 6, lane = tid & 63, lq = lane >> 4, lm = lane & 15;

    __shared__ _Float16 hsm[2][16 * 136];   // [buf][chain][h], +8 pad

    // Whh B-frags, register-resident for all 512 steps (64 VGPRs)
    half8_t bf[4][4];
    #pragma unroll
    for (int T = 0; T < 4; ++T) {
        #pragma unroll
        for (int kk = 0; kk < 4; ++kk) {
            const float* src = Whh + (size_t)(T * 128 + w * 16 + lm) * 128 + kk * 32 + lq * 8;
            half8_t h;
            #pragma unroll
            for (int j = 0; j < 8; ++j) h[j] = (_Float16)src[j];
            bf[T][kk] = h;
        }
    }

    for (int k = tid; k < 2 * 16 * 136; k += 512)
        ((_Float16*)hsm)[k] = (_Float16)0.0f;

    // per-(wave,lane) xp base; time stride = 8*64*16 halfs
    const _Float16* xp_wl = xp + ((size_t)wg * 512 * 8 + w) * 64 * 16 + (size_t)lane * 16;

    // preload xp for t=0
    int ta0 = dir ? (TT - 1) : 0;
    half8_t xca = *(const half8_t*)(xp_wl + (size_t)ta0 * 8192);
    half8_t xcb = *((const half8_t*)(xp_wl + (size_t)ta0 * 8192) + 1);
    __syncthreads();

    float c[4] = {0.f, 0.f, 0.f, 0.f};
    float hmax[4] = {-1e30f, -1e30f, -1e30f, -1e30f};

    for (int t = 0; t < TT; ++t) {
        const int buf = t & 1;

        // prefetch next step's xp (coalesced 32B/lane; hidden under MFMA+VALU)
        int tn = (t + 1 < TT) ? (t + 1) : t;
        int ta = dir ? (TT - 1 - tn) : tn;
        const half8_t* xsrc = (const half8_t*)(xp_wl + (size_t)ta * 8192);
        half8_t xna = xsrc[0], xnb = xsrc[1];

        // h A-frags (chain = lm): 4x ds_read_b128, conflict-free (136-half rows)
        half8_t af[4];
        #pragma unroll
        for (int kk = 0; kk < 4; ++kk)
            af[kk] = *(const half8_t*)&hsm[buf][lm * 136 + kk * 32 + lq * 8];

        // acc init from current xp (bias already folded in)
        float4_t acc[4];
        acc[0] = (float4_t){(float)xca[0], (float)xca[1], (float)xca[2], (float)xca[3]};
        acc[1] = (float4_t){(float)xca[4], (float)xca[5], (float)xca[6], (float)xca[7]};
        acc[2] = (float4_t){(float)xcb[0], (float)xcb[1], (float)xcb[2], (float)xcb[3]};
        acc[3] = (float4_t){(float)xcb[4], (float)xcb[5], (float)xcb[6], (float)xcb[7]};
        #pragma unroll
        for (int kk = 0; kk < 4; ++kk) {
            #pragma unroll
            for (int T = 0; T < 4; ++T)
                acc[T] = __builtin_amdgcn_mfma_f32_16x16x32_f16(af[kk], bf[T][kk], acc[T], 0, 0, 0);
        }

        // in-register gate math: lane's (chain = lq*4+r, h = w*16+lm)
        #pragma unroll
        for (int r = 0; r < 4; ++r) {
            float ig = sigmoidf_fast(acc[0][r]);
            float fg = sigmoidf_fast(acc[1][r]);
            float gg = tanhf_fast(acc[2][r]);
            float og = sigmoidf_fast(acc[3][r]);
            c[r] = fg * c[r] + ig * gg;
            float hv = og * tanhf_fast(c[r]);
            hmax[r] = fmaxf(hmax[r], hv);
            hsm[1 - buf][(lq * 4 + r) * 136 + w * 16 + lm] = (_Float16)hv;
        }

        xca = xna; xcb = xnb;
        __syncthreads();
    }

    #pragma unroll
    for (int r = 0; r < 4; ++r)
        pooled[(size_t)(bg * 16 + lq * 4 + r) * 256 + dir * HH + w * 16 + lm] = hmax[r];
}

// ---- kernel 3: pooled (128,256) -> relu(W1·+b1) -> sigmoid(W2·+b2) -> (128,1)
__global__ __launch_bounds__(64) void mlp_kernel(
    const float* __restrict__ pooled, const float* __restrict__ W1,
    const float* __restrict__ b1, const float* __restrict__ W2,
    const float* __restrict__ b2, float* __restrict__ out)
{
    const int b = blockIdx.x;
    const int j = threadIdx.x;
    const float4* p = (const float4*)(pooled + (size_t)b * 256);
    const float4* wv = (const float4*)(W1 + (size_t)j * 256);
    float s = 0.0f;
    #pragma unroll
    for (int q = 0; q < 64; ++q) {
        float4 pv = p[q];
        float4 ww = wv[q];
        s += pv.x * ww.x + pv.y * ww.y + pv.z * ww.z + pv.w * ww.w;
    }
    s += b1[j];
    s = fmaxf(s, 0.0f);
    float v = W2[j] * s;
    #pragma unroll
    for (int off = 32; off; off >>= 1) v += __shfl_down(v, off);
    if (j == 0) out[b] = 1.0f / (1.0f + __expf(-(v + b2[0])));
}

extern "C" void kernel_launch(void* const* d_in, const int* in_sizes, int n_in,
                              void* d_out, int out_size, void* d_ws, size_t ws_size,
                              hipStream_t stream) {
    const int*   x     = (const int*)d_in[0];
    const float* emb   = (const float*)d_in[1];
    const float* Wih_f = (const float*)d_in[2];
    const float* Whh_f = (const float*)d_in[3];
    const float* bih_f = (const float*)d_in[4];
    const float* bhh_f = (const float*)d_in[5];
    const float* Wih_b = (const float*)d_in[6];
    const float* Whh_b = (const float*)d_in[7];
    const float* bih_b = (const float*)d_in[8];
    const float* bhh_b = (const float*)d_in[9];
    const float* W1    = (const float*)d_in[10];
    const float* b1    = (const float*)d_in[11];
    const float* W2    = (const float*)d_in[12];
    const float* b2    = (const float*)d_in[13];
    float* out = (float*)d_out;

    char* ws = (char*)d_ws;
    float*    pooled = (float*)ws;                 // 128 KB
    _Float16* xp     = (_Float16*)(ws + 131072);   // 134.2 MB: 67,108,864 halfs

    hipLaunchKernelGGL(xp_gemm_kernel, dim3(16, 16), dim3(512), 0, stream,
                       x, emb, Wih_f, bih_f, bhh_f, Wih_b, bih_b, bhh_b, xp);
    hipLaunchKernelGGL(bilstm_rec_kernel, dim3(16), dim3(512), 0, stream,
                       xp, Whh_f, Whh_b, pooled);
    hipLaunchKernelGGL(mlp_kernel, dim3(128), dim3(64), 0, stream,
                       pooled, W1, b1, W2, b2, out);
}

// Round 6
// 586.781 us; speedup vs baseline: 1.5889x; 1.5817x over previous
//
#include <hip/hip_runtime.h>
#include <hip/hip_fp16.h>

#define TT 512
#define HH 128

typedef _Float16 half8_t __attribute__((ext_vector_type(8)));
typedef float    float4_t __attribute__((ext_vector_type(4)));

// ---- fast activations pinned to v_exp_f32 (2^x) / v_rcp_f32 ----
__device__ __forceinline__ float fast_exp2(float x) {
#if __has_builtin(__builtin_amdgcn_exp2f)
    return __builtin_amdgcn_exp2f(x);
#else
    float r; asm("v_exp_f32 %0, %1" : "=v"(r) : "v"(x)); return r;
#endif
}
__device__ __forceinline__ float fast_rcp(float x) {
#if __has_builtin(__builtin_amdgcn_rcpf)
    return __builtin_amdgcn_rcpf(x);
#else
    float r; asm("v_rcp_f32 %0, %1" : "=v"(r) : "v"(x)); return r;
#endif
}
__device__ __forceinline__ float sigmoid_fast(float x) {
    return fast_rcp(1.0f + fast_exp2(-1.4426950408889634f * x));
}
__device__ __forceinline__ float tanh_fast(float x) {
    return 2.0f * fast_rcp(1.0f + fast_exp2(-2.8853900817779268f * x)) - 1.0f;
}

// LDS-only barrier: waits lgkmcnt(0) but lets global loads (vmcnt) stay in
// flight across the barrier — removes the __syncthreads vmcnt(0) drain that
// serialized the xp HBM prefetch into every recurrence step.
__device__ __forceinline__ void wg_barrier_lds() {
#if __has_builtin(__builtin_amdgcn_s_waitcnt)
    __builtin_amdgcn_s_waitcnt(0xC07F);   // lgkmcnt(0), vmcnt=max, expcnt=max
#else
    asm volatile("s_waitcnt lgkmcnt(0)" ::: "memory");
#endif
    __builtin_amdgcn_s_barrier();
}

// xp layout (f16): half index = ((((dir*8+bg16)*512 + t)*8 + w)*64 + lane)*16 + (T*4+r)
__device__ __forceinline__ size_t xp_off(int dirbg, int t, int w, int lane) {
    return ((((size_t)dirbg * 512 + t) * 8 + w) * 64 + lane) * 16;
}

// ---- kernel 1: xp GEMM. WG=(dir*8+bg16, tchunk of 16): M=16 chains, N=512, K=128.
__global__ __attribute__((amdgpu_flat_work_group_size(512, 512), amdgpu_waves_per_eu(2, 2)))
void xp_gemm_kernel(
    const int* __restrict__ x, const float* __restrict__ emb,
    const float* __restrict__ Wih_f, const float* __restrict__ bih_f, const float* __restrict__ bhh_f,
    const float* __restrict__ Wih_b, const float* __restrict__ bih_b, const float* __restrict__ bhh_b,
    _Float16* __restrict__ xp)
{
    const int wg  = blockIdx.x;        // dir*8+bg16
    const int dir = wg >> 3, bg = wg & 7;
    const int tc  = blockIdx.y;        // t-base = tc*16

    const float* Wih = dir ? Wih_b : Wih_f;
    const float* bih = dir ? bih_b : bih_f;
    const float* bhh = dir ? bhh_b : bhh_f;

    const int tid = threadIdx.x;
    const int w = tid >> 6, lane = tid & 63, lq = lane >> 4, lm = lane & 15;

    __shared__ int id_sm[16 * 16];
    __shared__ _Float16 A[2][16 * 136];

    if (tid < 256) {
        int i = tid >> 4, j = tid & 15;
        id_sm[i * 16 + j] = x[(size_t)(bg * 16 + i) * TT + tc * 16 + j];
    }

    half8_t bf[4][4];
    float bias[4];
    #pragma unroll
    for (int T = 0; T < 4; ++T) {
        int gate = T * 128 + w * 16 + lm;
        bias[T] = bih[gate] + bhh[gate];
        #pragma unroll
        for (int kk = 0; kk < 4; ++kk) {
            const float* src = Wih + (size_t)gate * 128 + kk * 32 + lq * 8;
            half8_t h;
            #pragma unroll
            for (int j = 0; j < 8; ++j) h[j] = (_Float16)src[j];
            bf[T][kk] = h;
        }
    }
    __syncthreads();

    const int i = tid >> 5, seg = tid & 31;
    {
        int id = id_sm[i * 16];
        float4 v = *(const float4*)(emb + (size_t)id * 128 + seg * 4);
        _Float16* d = &A[0][i * 136 + seg * 4];
        d[0] = (_Float16)v.x; d[1] = (_Float16)v.y;
        d[2] = (_Float16)v.z; d[3] = (_Float16)v.w;
    }
    __syncthreads();

    for (int tp = 0; tp < 16; ++tp) {
        const int buf = tp & 1;
        float4 v;
        const bool havepre = (tp + 1 < 16);
        if (havepre) {
            int id = id_sm[i * 16 + tp + 1];
            v = *(const float4*)(emb + (size_t)id * 128 + seg * 4);
        }

        half8_t af[4];
        #pragma unroll
        for (int kk = 0; kk < 4; ++kk)
            af[kk] = *(const half8_t*)&A[buf][lm * 136 + kk * 32 + lq * 8];

        float4_t acc[4];
        #pragma unroll
        for (int T = 0; T < 4; ++T)
            acc[T] = (float4_t){bias[T], bias[T], bias[T], bias[T]};
        #pragma unroll
        for (int kk = 0; kk < 4; ++kk) {
            #pragma unroll
            for (int T = 0; T < 4; ++T)
                acc[T] = __builtin_amdgcn_mfma_f32_16x16x32_f16(af[kk], bf[T][kk], acc[T], 0, 0, 0);
        }

        half8_t p0, p1;
        #pragma unroll
        for (int T = 0; T < 2; ++T)
            #pragma unroll
            for (int r = 0; r < 4; ++r) p0[T * 4 + r] = (_Float16)acc[T][r];
        #pragma unroll
        for (int T = 2; T < 4; ++T)
            #pragma unroll
            for (int r = 0; r < 4; ++r) p1[(T - 2) * 4 + r] = (_Float16)acc[T][r];
        half8_t* dst = (half8_t*)(xp + xp_off(wg, tc * 16 + tp, w, lane));
        dst[0] = p0; dst[1] = p1;

        if (havepre) {
            _Float16* d = &A[1 - buf][i * 136 + seg * 4];
            d[0] = (_Float16)v.x; d[1] = (_Float16)v.y;
            d[2] = (_Float16)v.z; d[3] = (_Float16)v.w;
        }
        __syncthreads();
    }
}

// ---- kernel 2: recurrence. 64 WGs: (dir, bg16, s) -> 4 chains each (M=4).
// Same instruction stream as the 16-chain version (masked lanes are free) but
// 4x the CUs. Raw lgkm-only barrier + 4-buffer xp prefetch pipeline (depth 2):
// global loads stay in flight across barriers; consumer waits vmcnt(2), not 0.
__global__ __attribute__((amdgpu_flat_work_group_size(512, 512), amdgpu_waves_per_eu(2, 2)))
void bilstm_rec_kernel(
    const _Float16* __restrict__ xp,
    const float* __restrict__ Whh_f, const float* __restrict__ Whh_b,
    float* __restrict__ pooled)
{
    const int g    = blockIdx.x;       // 0..63
    const int dir  = g >> 5;
    const int bg16 = (g & 31) >> 2;
    const int s    = g & 3;
    const float* Whh = dir ? Whh_b : Whh_f;

    const int tid = threadIdx.x;
    const int w = tid >> 6, lane = tid & 63, lq = lane >> 4, lm = lane & 15;

    __shared__ _Float16 hsm[2][16 * 136];   // rows 0-3 live, rows 4-15 stay zero

    half8_t bf[4][4];
    #pragma unroll
    for (int T = 0; T < 4; ++T) {
        #pragma unroll
        for (int kk = 0; kk < 4; ++kk) {
            const float* src = Whh + (size_t)(T * 128 + w * 16 + lm) * 128 + kk * 32 + lq * 8;
            half8_t h;
            #pragma unroll
            for (int j = 0; j < 8; ++j) h[j] = (_Float16)src[j];
            bf[T][kk] = h;
        }
    }

    for (int k = tid; k < 2 * 16 * 136; k += 512)
        ((_Float16*)hsm)[k] = (_Float16)0.0f;

    // this WG's 4 chains are D-rows s*4+r -> stored at lanes s*16+lm in xp
    const _Float16* xp_wl = xp + ((size_t)(dir * 8 + bg16) * 512 * 8 + w) * 1024
                               + (size_t)(s * 16 + lm) * 16;

    // rotating 4-deep prefetch buffers
    half8_t Qa[4], Qb[4];
    {
        int ta = dir ? (TT - 1) : 0;
        const half8_t* p = (const half8_t*)(xp_wl + (size_t)ta * 8192);
        Qa[0] = p[0]; Qb[0] = p[1];
    }
    {
        int ta = dir ? (TT - 2) : 1;
        const half8_t* p = (const half8_t*)(xp_wl + (size_t)ta * 8192);
        Qa[1] = p[0]; Qb[1] = p[1];
    }
    __syncthreads();

    float c[4] = {0.f, 0.f, 0.f, 0.f};
    float hmax[4] = {-1e30f, -1e30f, -1e30f, -1e30f};

    for (int tb = 0; tb < TT; tb += 4) {
        #pragma unroll
        for (int P = 0; P < 4; ++P) {
            const int t = tb + P;
            {   // issue prefetch for t+2 into buffer (P+2)&3
                int tl = (t + 2 < TT) ? (t + 2) : (TT - 1);
                int ta = dir ? (TT - 1 - tl) : tl;
                const half8_t* pp = (const half8_t*)(xp_wl + (size_t)ta * 8192);
                Qa[(P + 2) & 3] = pp[0]; Qb[(P + 2) & 3] = pp[1];
            }

            half8_t af[4];
            #pragma unroll
            for (int kk = 0; kk < 4; ++kk)
                af[kk] = *(const half8_t*)&hsm[P & 1][lm * 136 + kk * 32 + lq * 8];

            float4_t acc[4];
            acc[0] = (float4_t){(float)Qa[P][0], (float)Qa[P][1], (float)Qa[P][2], (float)Qa[P][3]};
            acc[1] = (float4_t){(float)Qa[P][4], (float)Qa[P][5], (float)Qa[P][6], (float)Qa[P][7]};
            acc[2] = (float4_t){(float)Qb[P][0], (float)Qb[P][1], (float)Qb[P][2], (float)Qb[P][3]};
            acc[3] = (float4_t){(float)Qb[P][4], (float)Qb[P][5], (float)Qb[P][6], (float)Qb[P][7]};
            #pragma unroll
            for (int kk = 0; kk < 4; ++kk) {
                #pragma unroll
                for (int T = 0; T < 4; ++T)
                    acc[T] = __builtin_amdgcn_mfma_f32_16x16x32_f16(af[kk], bf[T][kk], acc[T], 0, 0, 0);
            }

            #pragma unroll
            for (int r = 0; r < 4; ++r) {
                float ig = sigmoid_fast(acc[0][r]);
                float fg = sigmoid_fast(acc[1][r]);
                float gg = tanh_fast(acc[2][r]);
                float og = sigmoid_fast(acc[3][r]);
                c[r] = fg * c[r] + ig * gg;
                float hv = og * tanh_fast(c[r]);
                hmax[r] = fmaxf(hmax[r], hv);
                if (lq == 0)
                    hsm[1 - (P & 1)][r * 136 + w * 16 + lm] = (_Float16)hv;
            }

            wg_barrier_lds();
        }
    }

    if (lq == 0) {
        #pragma unroll
        for (int r = 0; r < 4; ++r)
            pooled[(size_t)(bg16 * 16 + s * 4 + r) * 256 + dir * HH + w * 16 + lm] = hmax[r];
    }
}

// ---- kernel 3: pooled (128,256) -> relu(W1·+b1) -> sigmoid(W2·+b2) -> (128,1)
__global__ __launch_bounds__(64) void mlp_kernel(
    const float* __restrict__ pooled, const float* __restrict__ W1,
    const float* __restrict__ b1, const float* __restrict__ W2,
    const float* __restrict__ b2, float* __restrict__ out)
{
    const int b = blockIdx.x;
    const int j = threadIdx.x;
    const float4* p = (const float4*)(pooled + (size_t)b * 256);
    const float4* wv = (const float4*)(W1 + (size_t)j * 256);
    float s = 0.0f;
    #pragma unroll
    for (int q = 0; q < 64; ++q) {
        float4 pv = p[q];
        float4 ww = wv[q];
        s += pv.x * ww.x + pv.y * ww.y + pv.z * ww.z + pv.w * ww.w;
    }
    s += b1[j];
    s = fmaxf(s, 0.0f);
    float v = W2[j] * s;
    #pragma unroll
    for (int off = 32; off; off >>= 1) v += __shfl_down(v, off);
    if (j == 0) out[b] = 1.0f / (1.0f + __expf(-(v + b2[0])));
}

extern "C" void kernel_launch(void* const* d_in, const int* in_sizes, int n_in,
                              void* d_out, int out_size, void* d_ws, size_t ws_size,
                              hipStream_t stream) {
    const int*   x     = (const int*)d_in[0];
    const float* emb   = (const float*)d_in[1];
    const float* Wih_f = (const float*)d_in[2];
    const float* Whh_f = (const float*)d_in[3];
    const float* bih_f = (const float*)d_in[4];
    const float* bhh_f = (const float*)d_in[5];
    const float* Wih_b = (const float*)d_in[6];
    const float* Whh_b = (const float*)d_in[7];
    const float* bih_b = (const float*)d_in[8];
    const float* bhh_b = (const float*)d_in[9];
    const float* W1    = (const float*)d_in[10];
    const float* b1    = (const float*)d_in[11];
    const float* W2    = (const float*)d_in[12];
    const float* b2    = (const float*)d_in[13];
    float* out = (float*)d_out;

    char* ws = (char*)d_ws;
    float*    pooled = (float*)ws;                 // 128 KB
    _Float16* xp     = (_Float16*)(ws + 131072);   // 134.2 MB

    hipLaunchKernelGGL(xp_gemm_kernel, dim3(16, 32), dim3(512), 0, stream,
                       x, emb, Wih_f, bih_f, bhh_f, Wih_b, bih_b, bhh_b, xp);
    hipLaunchKernelGGL(bilstm_rec_kernel, dim3(64), dim3(512), 0, stream,
                       xp, Whh_f, Whh_b, pooled);
    hipLaunchKernelGGL(mlp_kernel, dim3(128), dim3(64), 0, stream,
                       pooled, W1, b1, W2, b2, out);
}